// Round 2
// baseline (291.984 us; speedup 1.0000x reference)
//
#include <hip/hip_runtime.h>
#include <math.h>

// ---------------------------------------------------------------------------
// GatedDirGCNConv — r12: hide projection work inside the atomic-bound kernel.
//   K1 projAB_zero: ONLY what edge_w needs: A,B fp32 + Ah,Bh bf16 + zero pk.
//                   No LDS: node loop index made wave-uniform (readfirstlane)
//                   so x-row loads are uniform-address (s_load / broadcast).
//   K2 edge_proj  : edge blocks (unchanged atomic-floor logic, ~80 µs with
//                   VALU 22% idle slack) + PB proj blocks computing HSh/HDh
//                   + 1 block for the Wg1 swizzle. Proj blocks use the idle
//                   VALU/SMEM pipes while TCC grinds atomics -> ~free.
//   K3 gather_gate: unchanged from r11 (4-node weight batching).
//   Post-mortem r11: launch_bounds(256,2) capped VGPR at 128 -> weight spill
//   ate the K1 saving; K3's cost is mbuf broadcasts, not Wg1q traffic.
// ---------------------------------------------------------------------------

typedef unsigned long long u64;

#define SLOTS 56   // max row len; P(Poisson(16) >= 56) ~ 5e-15 per side

__device__ __forceinline__ float bflo(unsigned u) { return __uint_as_float(u << 16); }
__device__ __forceinline__ float bfhi(unsigned u) { return __uint_as_float(u & 0xffff0000u); }
__device__ __forceinline__ unsigned rne16(float f) {   // fp32 -> bf16 bits, RNE
    unsigned u = __float_as_uint(f);
    return (u + 0x7fffu + ((u >> 16) & 1u)) >> 16;
}

// K1: A/B (fp32 + packed bf16) projection + zero pk. No LDS, no syncthreads.
// wv: side = wv&1 (A:Wl1-lo / B:Wl1-hi), par = wv>>1 (node parity, 32 nodes).
// x-row address is wave-uniform -> scalar-load eligible.
__global__ __launch_bounds__(256) void projAB_zero_kernel(
    const float* __restrict__ x,
    const float* __restrict__ Wl1, const float* __restrict__ bl1,
    float* __restrict__ A, float* __restrict__ B,
    unsigned* __restrict__ Ah, unsigned* __restrict__ Bh,
    int4* __restrict__ zp4, int nz4, int PB, int N)
{
    if (blockIdx.x >= PB) {                         // zero pk
        const int t0 = (blockIdx.x - PB) * 256 + threadIdx.x;
        const int stride = 64 * 256;
        const int4 z = make_int4(0, 0, 0, 0);
        for (int i = t0; i < nz4; i += stride) zp4[i] = z;
        return;
    }
    const int tid  = threadIdx.x;
    const int n0   = blockIdx.x * 64;
    const int wv   = tid >> 6;
    const int cc   = tid & 63;
    const int side = wv & 1;
    const int par  = __builtin_amdgcn_readfirstlane(wv >> 1);  // wave-uniform

    const float* W  = side ? (Wl1 + 64 * 64) : Wl1;
    const float  bv = side ? 0.f : bl1[cc];        // bl1 applied once (A side)
    float*    oA  = side ? B  : A;
    unsigned* oAh = side ? Bh : Ah;

    float w[64];
#pragma unroll
    for (int k = 0; k < 64; ++k) w[k] = W[k * 64 + cc];

    const int nmax = (N - n0 < 64) ? (N - n0) : 64;
    for (int n = par; n < nmax; n += 2) {
        const float* xr = x + (long)(n0 + n) * 64;  // uniform address
        float acc = bv;
#pragma unroll
        for (int k4 = 0; k4 < 16; ++k4) {
            const float4 xv = ((const float4*)xr)[k4];
            acc += xv.x * w[4 * k4]     + xv.y * w[4 * k4 + 1]
                 + xv.z * w[4 * k4 + 2] + xv.w * w[4 * k4 + 3];
        }
        const long gn = n0 + n;
        oA[gn * 64 + cc] = acc;
        const float p = __shfl_xor(acc, 1);         // partner feature cc^1
        if ((cc & 1) == 0)                          // even lane packs (cc, cc+1)
            oAh[gn * 32 + (cc >> 1)] = (rne16(p) << 16) | rne16(acc);
    }
}

// K2: [0,PB) proj HSh/HDh; [PB] Wg1 swizzle; (PB, ...) edge blocks.
// Edge logic unchanged — sits on the 1.6M u64-atomic floor (~76 µs); the proj
// blocks soak the idle VALU/SMEM slack of that floor.
#define LCS_MARGIN 0.04f
__global__ __launch_bounds__(256) void edge_proj_kernel(
    const int* __restrict__ src, const int* __restrict__ dst,
    const float* __restrict__ counts,
    const float* __restrict__ A, const float* __restrict__ B,
    const unsigned* __restrict__ Ah, const unsigned* __restrict__ Bh,
    const float* __restrict__ Wl2, const float* __restrict__ bl2,
    u64* __restrict__ pk, unsigned* __restrict__ rec,
    const float* __restrict__ x,
    const float* __restrict__ Ws2d, const float* __restrict__ bs2d,
    const float* __restrict__ Wd2s, const float* __restrict__ bd2s,
    unsigned* __restrict__ HSh, unsigned* __restrict__ HDh,
    const float* __restrict__ Wg1, float* __restrict__ Wg1q,
    int PB, int N, int E)
{
    const int tid = threadIdx.x;

    if (blockIdx.x < PB) {                          // HS/HD projection block
        const int n0   = blockIdx.x * 64;
        const int wv   = tid >> 6;
        const int cc   = tid & 63;
        const int side = wv & 1;                    // 0: Ws2d->HSh, 1: Wd2s->HDh
        const int par  = __builtin_amdgcn_readfirstlane(wv >> 1);

        const float* W  = side ? Wd2s : Ws2d;
        const float  bv = side ? bd2s[cc] : bs2d[cc];
        unsigned* oH = side ? HDh : HSh;

        float w[64];
#pragma unroll
        for (int k = 0; k < 64; ++k) w[k] = W[k * 64 + cc];

        const int nmax = (N - n0 < 64) ? (N - n0) : 64;
        for (int n = par; n < nmax; n += 2) {
            const float* xr = x + (long)(n0 + n) * 64;   // uniform address
            float acc = bv;
#pragma unroll
            for (int k4 = 0; k4 < 16; ++k4) {
                const float4 xv = ((const float4*)xr)[k4];
                acc += xv.x * w[4 * k4]     + xv.y * w[4 * k4 + 1]
                     + xv.z * w[4 * k4 + 2] + xv.w * w[4 * k4 + 3];
            }
            const float p = __shfl_xor(acc, 1);
            if ((cc & 1) == 0)
                oH[((long)(n0 + n)) * 32 + (cc >> 1)] = (rne16(p) << 16) | rne16(acc);
        }
        return;
    }
    if (blockIdx.x == PB) {                         // Wg1 swizzle
        for (int i = tid; i < 8192; i += 256) {
            const int k = i >> 6, c = i & 63;
            Wg1q[((k >> 2) * 64 + c) * 4 + (k & 3)] = Wg1[i];
        }
        return;
    }

    const int e = (blockIdx.x - PB - 1) * 32 + (tid >> 3);
    const int c = tid & 7;                          // features 8c..8c+7
    if (e >= E) return;

    const int s = src[e];
    const int d = dst[e];
    const uint4  ua  = *((const uint4*)(Ah + (long)s * 32 + c * 4));
    const uint4  ub  = *((const uint4*)(Bh + (long)d * 32 + c * 4));
    const float4 wl0 = *((const float4*)(Wl2 + c * 8));
    const float4 wl1 = *((const float4*)(Wl2 + c * 8 + 4));

    float p = fmaxf(bflo(ua.x) + bflo(ub.x), 0.f) * wl0.x
            + fmaxf(bfhi(ua.x) + bfhi(ub.x), 0.f) * wl0.y
            + fmaxf(bflo(ua.y) + bflo(ub.y), 0.f) * wl0.z
            + fmaxf(bfhi(ua.y) + bfhi(ub.y), 0.f) * wl0.w
            + fmaxf(bflo(ua.z) + bflo(ub.z), 0.f) * wl1.x
            + fmaxf(bfhi(ua.z) + bfhi(ub.z), 0.f) * wl1.y
            + fmaxf(bflo(ua.w) + bflo(ub.w), 0.f) * wl1.z
            + fmaxf(bfhi(ua.w) + bfhi(ub.w), 0.f) * wl1.w;
    p += __shfl_xor(p, 1); p += __shfl_xor(p, 2); p += __shfl_xor(p, 4);

    float z = p + bl2[0];
    if (fabsf(z) < LCS_MARGIN) {        // borderline (~3%): exact fp32 recheck
        const float4 a0 = *((const float4*)(A + (long)s * 64 + c * 8));
        const float4 a1 = *((const float4*)(A + (long)s * 64 + c * 8 + 4));
        const float4 b0 = *((const float4*)(B + (long)d * 64 + c * 8));
        const float4 b1 = *((const float4*)(B + (long)d * 64 + c * 8 + 4));
        float q = fmaxf(a0.x + b0.x, 0.f) * wl0.x + fmaxf(a0.y + b0.y, 0.f) * wl0.y
                + fmaxf(a0.z + b0.z, 0.f) * wl0.z + fmaxf(a0.w + b0.w, 0.f) * wl0.w
                + fmaxf(a1.x + b1.x, 0.f) * wl1.x + fmaxf(a1.y + b1.y, 0.f) * wl1.y
                + fmaxf(a1.z + b1.z, 0.f) * wl1.z + fmaxf(a1.w + b1.w, 0.f) * wl1.w;
        q += __shfl_xor(q, 1); q += __shfl_xor(q, 2); q += __shfl_xor(q, 4);
        z = q + bl2[0];
    }

    if (c == 0) {
        const u64 keep = (z >= 0.f) ? 1ull : 0ull;   // sigmoid(z)>=0.5 <=> z>=0
        const unsigned ic = (unsigned)__float2int_rn(counts[e]);  // {1..4} exact
        const u64 od = atomicAdd(pk + d,     (keep << 32) | (u64)ic);
        const u64 os = atomicAdd(pk + N + s, (keep << 32) | (u64)ic);
        if (keep) {
            rec[(long)d * SLOTS + (int)(od >> 32)]       = ((unsigned)s << 16) | ic;
            rec[(long)(N + s) * SLOTS + (int)(os >> 32)] = ((unsigned)d << 16) | ic;
        }
    }
}

// K3: one wave per 4 nodes; gather each node (8 groups x 8 bf16 feats), then
// the gate MLP batches 4 nodes per Wg1q fragment. (unchanged from r11)
__global__ __launch_bounds__(256) void gather_gate_kernel(
    const u64* __restrict__ pk, const unsigned* __restrict__ rec,
    const unsigned* __restrict__ HSh, const unsigned* __restrict__ HDh,
    const float* __restrict__ x,
    const float* __restrict__ Wg1q, const float* __restrict__ bg1,
    const float* __restrict__ Wg2, const float* __restrict__ bg2,
    float* __restrict__ out, int N)
{
    __shared__ float mbuf[16][128];
    const int tid  = threadIdx.x;
    const int wv   = tid >> 6;
    const int lane = tid & 63;
    const int g    = lane >> 3;        // edge group 0..7
    const int c    = lane & 7;         // feature slice: features 8c..8c+7
    const int nb   = blockIdx.x * 16 + wv * 4;     // first node of this wave

    const unsigned* pklo = (const unsigned*)pk;    // lo32 of pk[i] at index 2i

    for (int j = 0; j < 4; ++j) {
        const int n   = nb + j;
        const int row = wv * 4 + j;
        if (n >= N) {
            if (g == 0) {
#pragma unroll
                for (int q = 0; q < 8; ++q) {
                    mbuf[row][c * 8 + q]      = 0.f;
                    mbuf[row][64 + c * 8 + q] = 0.f;
                }
            }
            continue;
        }

        const u64 pin  = pk[n];
        const u64 pout = pk[N + n];
        const int ei = (int)(pin >> 32);
        const int eo = (int)(pout >> 32);
        const float qin  = 1.f / sqrtf(fmaxf((float)(unsigned)pin,  1.f)); // isq_in[n]
        const float qout = 1.f / sqrtf(fmaxf((float)(unsigned)pout, 1.f)); // isq_out[n]
        const unsigned* rin  = rec + (long)n * SLOTS;
        const unsigned* rout = rec + (long)(N + n) * SLOTS;

        float mi[8], mo[8];
#pragma unroll
        for (int q = 0; q < 8; ++q) { mi[q] = 0.f; mo[q] = 0.f; }

        int ii = g, jo = g;
        while ((ii < ei) || (jo < eo)) {
            const bool pa = ii < ei;
            const bool pb = jo < eo;
            const unsigned ra = rin[pa ? ii : 0];      // clamped: slot0 junk*0 safe
            const unsigned rb = rout[pb ? jo : 0];
            const unsigned sa = ra >> 16;              // src node (m_in side)
            const unsigned sb = rb >> 16;              // dst node (m_out side)
            // w/row-factor: cnt * rsqrt(deg of the other endpoint)
            const float dga = (float)pklo[2 * (N + (int)sa)];   // deg_out[sa]
            const float dgb = (float)pklo[2 * (int)sb];         // deg_in[sb]
            const float wa = pa ? (float)(ra & 0xFFu) * (1.f / sqrtf(fmaxf(dga, 1.f))) : 0.f;
            const float wb = pb ? (float)(rb & 0xFFu) * (1.f / sqrtf(fmaxf(dgb, 1.f))) : 0.f;
            const uint4 ua = *((const uint4*)(HSh + (long)sa * 32 + c * 4));
            const uint4 ub = *((const uint4*)(HDh + (long)sb * 32 + c * 4));
            mi[0] += wa * bflo(ua.x);  mo[0] += wb * bflo(ub.x);
            mi[1] += wa * bfhi(ua.x);  mo[1] += wb * bfhi(ub.x);
            mi[2] += wa * bflo(ua.y);  mo[2] += wb * bflo(ub.y);
            mi[3] += wa * bfhi(ua.y);  mo[3] += wb * bfhi(ub.y);
            mi[4] += wa * bflo(ua.z);  mo[4] += wb * bflo(ub.z);
            mi[5] += wa * bfhi(ua.z);  mo[5] += wb * bfhi(ub.z);
            mi[6] += wa * bflo(ua.w);  mo[6] += wb * bflo(ub.w);
            mi[7] += wa * bfhi(ua.w);  mo[7] += wb * bfhi(ub.w);
            ii += 8; jo += 8;
        }

        // reduce the 8 edge groups (lane bits 3,4,5)
#pragma unroll
        for (int q = 0; q < 8; ++q) {
            mi[q] += __shfl_xor(mi[q], 8);
            mi[q] += __shfl_xor(mi[q], 16);
            mi[q] += __shfl_xor(mi[q], 32);
            mo[q] += __shfl_xor(mo[q], 8);
            mo[q] += __shfl_xor(mo[q], 16);
            mo[q] += __shfl_xor(mo[q], 32);
        }
        if (g == 0) {
#pragma unroll
            for (int q = 0; q < 8; ++q) {
                mbuf[row][c * 8 + q]      = mi[q] * qin;    // apply row norm factor
                mbuf[row][64 + c * 8 + q] = mo[q] * qout;
            }
        }
    }
    // wave-local LDS RAW; compiler inserts lgkmcnt wait (no barrier needed)

    const float bgv = bg1[lane];
    float ac0 = bgv, ac1 = bgv, ac2 = bgv, ac3 = bgv;
    const float* m0 = &mbuf[wv * 4 + 0][0];
    const float* m1 = &mbuf[wv * 4 + 1][0];
    const float* m2 = &mbuf[wv * 4 + 2][0];
    const float* m3 = &mbuf[wv * 4 + 3][0];
#pragma unroll 4
    for (int k4 = 0; k4 < 32; ++k4) {
        const float4 w4 = ((const float4*)Wg1q)[k4 * 64 + lane];   // coalesced, L1
        const float4 q0 = ((const float4*)m0)[k4];                 // LDS broadcast
        const float4 q1 = ((const float4*)m1)[k4];
        const float4 q2 = ((const float4*)m2)[k4];
        const float4 q3 = ((const float4*)m3)[k4];
        ac0 += q0.x * w4.x + q0.y * w4.y + q0.z * w4.z + q0.w * w4.w;
        ac1 += q1.x * w4.x + q1.y * w4.y + q1.z * w4.z + q1.w * w4.w;
        ac2 += q2.x * w4.x + q2.y * w4.y + q2.z * w4.z + q2.w * w4.w;
        ac3 += q3.x * w4.x + q3.y * w4.y + q3.z * w4.z + q3.w * w4.w;
    }
    const float wg2 = Wg2[lane];
    float v0 = fmaxf(ac0, 0.f) * wg2;
    float v1 = fmaxf(ac1, 0.f) * wg2;
    float v2 = fmaxf(ac2, 0.f) * wg2;
    float v3 = fmaxf(ac3, 0.f) * wg2;
#pragma unroll
    for (int m = 1; m <= 32; m <<= 1) {
        v0 += __shfl_xor(v0, m);
        v1 += __shfl_xor(v1, m);
        v2 += __shfl_xor(v2, m);
        v3 += __shfl_xor(v3, m);
    }
    const float bb = bg2[0];
    float gt[4];
    gt[0] = 1.f / (1.f + expf(-(v0 + bb)));
    gt[1] = 1.f / (1.f + expf(-(v1 + bb)));
    gt[2] = 1.f / (1.f + expf(-(v2 + bb)));
    gt[3] = 1.f / (1.f + expf(-(v3 + bb)));

#pragma unroll
    for (int j = 0; j < 4; ++j) {
        const int n = nb + j;
        if (n >= N) continue;
        const float miv = mbuf[wv * 4 + j][lane];
        const float mov = mbuf[wv * 4 + j][64 + lane];
        out[(long)n * 64 + lane] = 0.5f * gt[j] * miv + 0.5f * (1.f - gt[j]) * mov
                                 + x[(long)n * 64 + lane];
    }
}

extern "C" void kernel_launch(void* const* d_in, const int* in_sizes, int n_in,
                              void* d_out, int out_size, void* d_ws, size_t ws_size,
                              hipStream_t stream) {
    const float* x      = (const float*)d_in[0];
    const float* counts = (const float*)d_in[1];
    const float* Ws2d   = (const float*)d_in[2];
    const float* bs2d   = (const float*)d_in[3];
    const float* Wd2s   = (const float*)d_in[4];
    const float* bd2s   = (const float*)d_in[5];
    const float* Wl1    = (const float*)d_in[6];
    const float* bl1    = (const float*)d_in[7];
    const float* Wl2    = (const float*)d_in[8];
    const float* bl2    = (const float*)d_in[9];
    const float* Wg1    = (const float*)d_in[10];
    const float* bg1    = (const float*)d_in[11];
    const float* Wg2    = (const float*)d_in[12];
    const float* bg2    = (const float*)d_in[13];
    const int*   src    = (const int*)d_in[14];
    const int*   dst    = (const int*)d_in[15];

    const int N  = in_sizes[0] / 64;
    const int E  = in_sizes[14];
    const int PB = (N + 63) / 64;              // proj blocks

    float* ws      = (float*)d_ws;
    float* Wg1q    = ws;                       // 8192 floats
    float* A       = ws + 8192;                // 64N fp32
    float* B       = A + 64L * N;              // 64N fp32
    unsigned* Ah   = (unsigned*)(B + 64L * N); // 32N packed bf16
    unsigned* Bh   = Ah + 32L * N;
    unsigned* HSh  = Bh + 32L * N;
    unsigned* HDh  = HSh + 32L * N;
    u64* pk        = (u64*)(HDh + 32L * N);    // 2N u64 (even offset -> 8B ok)
    unsigned* rec  = (unsigned*)(pk + 2L * N); // 2N * SLOTS u32 (padded rows)

    projAB_zero_kernel<<<PB + 64, 256, 0, stream>>>(
        x, Wl1, bl1, A, B, Ah, Bh, (int4*)pk, N, PB, N);   // 2N u64 = N int4

    edge_proj_kernel<<<PB + 1 + (E + 31) / 32, 256, 0, stream>>>(
        src, dst, counts, A, B, Ah, Bh, Wl2, bl2, pk, rec,
        x, Ws2d, bs2d, Wd2s, bd2s, HSh, HDh, Wg1, Wg1q, PB, N, E);

    gather_gate_kernel<<<(N + 15) / 16, 256, 0, stream>>>(
        pk, rec, HSh, HDh, x, Wg1q, bg1, Wg2, bg2, (float*)d_out, N);
}

// Round 3
// 278.293 us; speedup vs baseline: 1.0492x; 1.0492x over previous
//
#include <hip/hip_runtime.h>
#include <math.h>

// ---------------------------------------------------------------------------
// GatedDirGCNConv — r13: r10 structure + cache-line-padded atomic counters.
//   The ONLY change vs the measured-278µs r10: pk[] padded to one u64 per
//   64B cache line (PKS=8). Packed pk had 8 node-counters/line -> ~128
//   atomic RMWs per TCC line (16/node x 8 nodes) -> line-granular
//   serialization was the real "atomic floor". Padding spreads the 1.6M
//   atomics over 8x more lines/channels; per-address (16/node) serialization
//   remains but is cheap.
//   K1 proj_zero : r10 version (LDS-staged 4-matrix projection; zero blocks
//                  now clear 6.4MB instead of 0.8MB).
//   K2 edge_w    : r10 version, pk indices scaled by PKS.
//   K3 gather_gate: r10 version (1 wave/node), pk/pklo indices scaled.
// ---------------------------------------------------------------------------

typedef unsigned long long u64;

#define SLOTS 56   // max row len; P(Poisson(16) >= 56) ~ 5e-15 per side
#define PKS   8    // u64 stride per pk entry: 64B = 1 cache line per counter

__device__ __forceinline__ float bflo(unsigned u) { return __uint_as_float(u << 16); }
__device__ __forceinline__ float bfhi(unsigned u) { return __uint_as_float(u & 0xffff0000u); }
__device__ __forceinline__ unsigned rne16(float f) {   // fp32 -> bf16 bits, RNE
    unsigned u = __float_as_uint(f);
    return (u + 0x7fffu + ((u >> 16) & 1u)) >> 16;
}

// K1: fused node projection + zero pk + swizzle Wg1.  (r10 version)
__global__ __launch_bounds__(256) void proj_zero_kernel(
    const float* __restrict__ x,
    const float* __restrict__ Wl1,  const float* __restrict__ bl1,
    const float* __restrict__ Ws2d, const float* __restrict__ bs2d,
    const float* __restrict__ Wd2s, const float* __restrict__ bd2s,
    const float* __restrict__ Wg1,  float* __restrict__ Wg1q,
    float* __restrict__ A, float* __restrict__ B,
    unsigned* __restrict__ Ah, unsigned* __restrict__ Bh,
    unsigned* __restrict__ HSh, unsigned* __restrict__ HDh,
    int4* __restrict__ zp4, int nz4, int PB, int N)
{
    if (blockIdx.x >= PB) {
        if (blockIdx.x == PB + 64) {               // Wg1 swizzle
            for (int i = threadIdx.x; i < 8192; i += 256) {
                const int k = i >> 6, c = i & 63;
                Wg1q[((k >> 2) * 64 + c) * 4 + (k & 3)] = Wg1[i];
            }
            return;
        }
        const int t0 = (blockIdx.x - PB) * 256 + threadIdx.x;   // zero pk
        const int stride = 64 * 256;
        const int4 z = make_int4(0, 0, 0, 0);
        for (int i = t0; i < nz4; i += stride) zp4[i] = z;
        return;
    }
    __shared__ float xs[64][64];
    const int tid = threadIdx.x;
    const int n0  = blockIdx.x * 64;
    const int wv  = tid >> 6;
    const int cc  = tid & 63;

    const float* Wbase; const float* bias; float* obase; unsigned* obh;
    switch (wv) {
        case 0:  Wbase = Wl1;           bias = bl1;     obase = A;       obh = Ah;  break;
        case 1:  Wbase = Wl1 + 64 * 64; bias = nullptr; obase = B;       obh = Bh;  break;
        case 2:  Wbase = Ws2d;          bias = bs2d;    obase = nullptr; obh = HSh; break;
        default: Wbase = Wd2s;          bias = bd2s;    obase = nullptr; obh = HDh; break;
    }

    float wr[64];
#pragma unroll
    for (int k = 0; k < 64; ++k) wr[k] = Wbase[k * 64 + cc];
    const float bv = bias ? bias[cc] : 0.f;

#pragma unroll
    for (int j = 0; j < 4; ++j) {
        int f4  = tid + j * 256;
        int row = f4 >> 4;
        int c4  = f4 & 15;
        int gn  = n0 + row;
        float4 v = (gn < N) ? ((const float4*)x)[(long)gn * 16 + c4]
                            : make_float4(0.f, 0.f, 0.f, 0.f);
        ((float4*)&xs[row][0])[c4] = v;
    }
    __syncthreads();

    const int nmax = (N - n0 < 64) ? (N - n0) : 64;
    for (int n = 0; n < nmax; ++n) {
        float acc = bv;
#pragma unroll
        for (int k = 0; k < 64; k += 4) {
            float4 xv = *((const float4*)&xs[n][k]);
            acc += xv.x * wr[k] + xv.y * wr[k + 1] + xv.z * wr[k + 2] + xv.w * wr[k + 3];
        }
        if (obase) obase[(long)(n0 + n) * 64 + cc] = acc;
        const float part = __shfl_xor(acc, 1);     // partner feature cc^1
        if ((cc & 1) == 0)                         // even lane packs (cc, cc+1)
            obh[(long)(n0 + n) * 32 + (cc >> 1)] = (rne16(part) << 16) | rne16(acc);
    }
}

// K2: LCS keep + u64 atomics (line-padded) + direct padded-row records.
// pk[i*PKS]: i in [0,N) = dst side, [N,2N) = src side.
#define LCS_MARGIN 0.04f
__global__ __launch_bounds__(256) void edge_w_kernel(
    const int* __restrict__ src, const int* __restrict__ dst,
    const float* __restrict__ counts,
    const float* __restrict__ A, const float* __restrict__ B,
    const unsigned* __restrict__ Ah, const unsigned* __restrict__ Bh,
    const float* __restrict__ Wl2, const float* __restrict__ bl2,
    u64* __restrict__ pk, unsigned* __restrict__ rec, int N, int E)
{
    const int tid = threadIdx.x;
    const int e   = blockIdx.x * 32 + (tid >> 3);
    const int c   = tid & 7;                     // features 8c..8c+7
    if (e >= E) return;

    const int s = src[e];
    const int d = dst[e];
    const uint4  ua  = *((const uint4*)(Ah + (long)s * 32 + c * 4));
    const uint4  ub  = *((const uint4*)(Bh + (long)d * 32 + c * 4));
    const float4 wl0 = *((const float4*)(Wl2 + c * 8));
    const float4 wl1 = *((const float4*)(Wl2 + c * 8 + 4));

    float p = fmaxf(bflo(ua.x) + bflo(ub.x), 0.f) * wl0.x
            + fmaxf(bfhi(ua.x) + bfhi(ub.x), 0.f) * wl0.y
            + fmaxf(bflo(ua.y) + bflo(ub.y), 0.f) * wl0.z
            + fmaxf(bfhi(ua.y) + bfhi(ub.y), 0.f) * wl0.w
            + fmaxf(bflo(ua.z) + bflo(ub.z), 0.f) * wl1.x
            + fmaxf(bfhi(ua.z) + bfhi(ub.z), 0.f) * wl1.y
            + fmaxf(bflo(ua.w) + bflo(ub.w), 0.f) * wl1.z
            + fmaxf(bfhi(ua.w) + bfhi(ub.w), 0.f) * wl1.w;
    p += __shfl_xor(p, 1); p += __shfl_xor(p, 2); p += __shfl_xor(p, 4);

    float z = p + bl2[0];
    if (fabsf(z) < LCS_MARGIN) {        // borderline (~3%): exact fp32 recheck
        const float4 a0 = *((const float4*)(A + (long)s * 64 + c * 8));
        const float4 a1 = *((const float4*)(A + (long)s * 64 + c * 8 + 4));
        const float4 b0 = *((const float4*)(B + (long)d * 64 + c * 8));
        const float4 b1 = *((const float4*)(B + (long)d * 64 + c * 8 + 4));
        float q = fmaxf(a0.x + b0.x, 0.f) * wl0.x + fmaxf(a0.y + b0.y, 0.f) * wl0.y
                + fmaxf(a0.z + b0.z, 0.f) * wl0.z + fmaxf(a0.w + b0.w, 0.f) * wl0.w
                + fmaxf(a1.x + b1.x, 0.f) * wl1.x + fmaxf(a1.y + b1.y, 0.f) * wl1.y
                + fmaxf(a1.z + b1.z, 0.f) * wl1.z + fmaxf(a1.w + b1.w, 0.f) * wl1.w;
        q += __shfl_xor(q, 1); q += __shfl_xor(q, 2); q += __shfl_xor(q, 4);
        z = q + bl2[0];
    }

    if (c == 0) {
        const u64 keep = (z >= 0.f) ? 1ull : 0ull;   // sigmoid(z)>=0.5 <=> z>=0
        const unsigned ic = (unsigned)__float2int_rn(counts[e]);  // {1..4} exact
        const u64 od = atomicAdd(pk + (long)d * PKS,       (keep << 32) | (u64)ic);
        const u64 os = atomicAdd(pk + (long)(N + s) * PKS, (keep << 32) | (u64)ic);
        if (keep) {
            rec[(long)d * SLOTS + (int)(od >> 32)]       = ((unsigned)s << 16) | ic;
            rec[(long)(N + s) * SLOTS + (int)(os >> 32)] = ((unsigned)d << 16) | ic;
        }
    }
}

// K3: one wave/node; merged in/out gather (8 groups x 8 bf16 feats);
// w computed inline: cnt * rsqrt(deg_other) [row factor hoisted]; gate+blend.
__global__ __launch_bounds__(256) void gather_gate_kernel(
    const u64* __restrict__ pk, const unsigned* __restrict__ rec,
    const unsigned* __restrict__ HSh, const unsigned* __restrict__ HDh,
    const float* __restrict__ x,
    const float* __restrict__ Wg1q, const float* __restrict__ bg1,
    const float* __restrict__ Wg2, const float* __restrict__ bg2,
    float* __restrict__ out, int N)
{
    __shared__ float mbuf[4][128];
    const int tid  = threadIdx.x;
    const int wv   = tid >> 6;
    const int lane = tid & 63;
    const int g    = lane >> 3;        // edge group 0..7
    const int c    = lane & 7;         // feature slice: features 8c..8c+7
    const int n    = blockIdx.x * 4 + wv;
    if (n >= N) return;

    const unsigned* pklo = (const unsigned*)pk;    // lo32 of pk[i*PKS] at 2*PKS*i

    const u64 pin  = pk[(long)n * PKS];
    const u64 pout = pk[(long)(N + n) * PKS];
    const int ei = (int)(pin >> 32);
    const int eo = (int)(pout >> 32);
    const float qin  = 1.f / sqrtf(fmaxf((float)(unsigned)pin,  1.f)); // isq_in[n]
    const float qout = 1.f / sqrtf(fmaxf((float)(unsigned)pout, 1.f)); // isq_out[n]
    const unsigned* rin  = rec + (long)n * SLOTS;
    const unsigned* rout = rec + (long)(N + n) * SLOTS;

    float mi[8], mo[8];
#pragma unroll
    for (int j = 0; j < 8; ++j) { mi[j] = 0.f; mo[j] = 0.f; }

    int ii = g, jo = g;
    while ((ii < ei) || (jo < eo)) {
        const bool pa = ii < ei;
        const bool pb = jo < eo;
        const unsigned ra = rin[pa ? ii : 0];      // clamped: slot0 junk*0 is safe
        const unsigned rb = rout[pb ? jo : 0];
        const unsigned sa = ra >> 16;              // src node (m_in side)
        const unsigned sb = rb >> 16;              // dst node (m_out side)
        // w/row-factor: cnt * rsqrt(deg of the other endpoint)
        const float dga = (float)pklo[2 * PKS * (N + (long)sa)];   // deg_out[sa]
        const float dgb = (float)pklo[2 * PKS * (long)sb];         // deg_in[sb]
        const float wa = pa ? (float)(ra & 0xFFu) * (1.f / sqrtf(fmaxf(dga, 1.f))) : 0.f;
        const float wb = pb ? (float)(rb & 0xFFu) * (1.f / sqrtf(fmaxf(dgb, 1.f))) : 0.f;
        const uint4 ua = *((const uint4*)(HSh + (long)sa * 32 + c * 4));
        const uint4 ub = *((const uint4*)(HDh + (long)sb * 32 + c * 4));
        mi[0] += wa * bflo(ua.x);  mo[0] += wb * bflo(ub.x);
        mi[1] += wa * bfhi(ua.x);  mo[1] += wb * bfhi(ub.x);
        mi[2] += wa * bflo(ua.y);  mo[2] += wb * bflo(ub.y);
        mi[3] += wa * bfhi(ua.y);  mo[3] += wb * bfhi(ub.y);
        mi[4] += wa * bflo(ua.z);  mo[4] += wb * bflo(ub.z);
        mi[5] += wa * bfhi(ua.z);  mo[5] += wb * bfhi(ub.z);
        mi[6] += wa * bflo(ua.w);  mo[6] += wb * bflo(ub.w);
        mi[7] += wa * bfhi(ua.w);  mo[7] += wb * bfhi(ub.w);
        ii += 8; jo += 8;
    }

    // reduce the 8 edge groups (lane bits 3,4,5)
#pragma unroll
    for (int j = 0; j < 8; ++j) {
        mi[j] += __shfl_xor(mi[j], 8);
        mi[j] += __shfl_xor(mi[j], 16);
        mi[j] += __shfl_xor(mi[j], 32);
        mo[j] += __shfl_xor(mo[j], 8);
        mo[j] += __shfl_xor(mo[j], 16);
        mo[j] += __shfl_xor(mo[j], 32);
    }
    if (g == 0) {
#pragma unroll
        for (int j = 0; j < 8; ++j) {
            mbuf[wv][c * 8 + j]      = mi[j] * qin;    // apply row norm factor
            mbuf[wv][64 + c * 8 + j] = mo[j] * qout;
        }
    }
    // wave-local LDS RAW; compiler inserts lgkmcnt wait

    float acc = bg1[lane];
    const float* mb = &mbuf[wv][0];
#pragma unroll 8
    for (int k4 = 0; k4 < 32; ++k4) {
        const float4 m4 = ((const float4*)mb)[k4];                 // LDS broadcast
        const float4 w4 = ((const float4*)Wg1q)[k4 * 64 + lane];   // coalesced, L1
        acc += m4.x * w4.x + m4.y * w4.y + m4.z * w4.z + m4.w * w4.w;
    }
    float v = fmaxf(acc, 0.f) * Wg2[lane];
    v += __shfl_xor(v, 1);  v += __shfl_xor(v, 2);  v += __shfl_xor(v, 4);
    v += __shfl_xor(v, 8);  v += __shfl_xor(v, 16); v += __shfl_xor(v, 32);

    const float gate = 1.f / (1.f + expf(-(v + bg2[0])));
    const float miv = mb[lane];
    const float mov = mb[64 + lane];
    out[(long)n * 64 + lane] = 0.5f * gate * miv + 0.5f * (1.f - gate) * mov
                             + x[(long)n * 64 + lane];
}

extern "C" void kernel_launch(void* const* d_in, const int* in_sizes, int n_in,
                              void* d_out, int out_size, void* d_ws, size_t ws_size,
                              hipStream_t stream) {
    const float* x      = (const float*)d_in[0];
    const float* counts = (const float*)d_in[1];
    const float* Ws2d   = (const float*)d_in[2];
    const float* bs2d   = (const float*)d_in[3];
    const float* Wd2s   = (const float*)d_in[4];
    const float* bd2s   = (const float*)d_in[5];
    const float* Wl1    = (const float*)d_in[6];
    const float* bl1    = (const float*)d_in[7];
    const float* Wl2    = (const float*)d_in[8];
    const float* bl2    = (const float*)d_in[9];
    const float* Wg1    = (const float*)d_in[10];
    const float* bg1    = (const float*)d_in[11];
    const float* Wg2    = (const float*)d_in[12];
    const float* bg2    = (const float*)d_in[13];
    const int*   src    = (const int*)d_in[14];
    const int*   dst    = (const int*)d_in[15];

    const int N  = in_sizes[0] / 64;
    const int E  = in_sizes[14];
    const int PB = (N + 63) / 64;              // proj blocks

    float* ws      = (float*)d_ws;
    float* Wg1q    = ws;                       // 8192 floats
    float* A       = ws + 8192;                // 64N fp32
    float* B       = A + 64L * N;              // 64N fp32
    unsigned* Ah   = (unsigned*)(B + 64L * N); // 32N packed bf16
    unsigned* Bh   = Ah + 32L * N;
    unsigned* HSh  = Bh + 32L * N;
    unsigned* HDh  = HSh + 32L * N;
    u64* pk        = (u64*)(HDh + 32L * N);    // 2N padded counters (64B each)
    unsigned* rec  = (unsigned*)(pk + 2L * N * PKS); // 2N * SLOTS u32

    const int nz4 = (int)(2L * N * PKS / 2);   // 2N*PKS u64 = N*PKS int4

    proj_zero_kernel<<<PB + 65, 256, 0, stream>>>(
        x, Wl1, bl1, Ws2d, bs2d, Wd2s, bd2s, Wg1, Wg1q,
        A, B, Ah, Bh, HSh, HDh, (int4*)pk, nz4, PB, N);

    edge_w_kernel<<<(E + 31) / 32, 256, 0, stream>>>(
        src, dst, counts, A, B, Ah, Bh, Wl2, bl2, pk, rec, N, E);

    gather_gate_kernel<<<(N + 3) / 4, 256, 0, stream>>>(
        pk, rec, HSh, HDh, x, Wg1q, bg1, Wg2, bg2, (float*)d_out, N);
}

// Round 4
// 276.956 us; speedup vs baseline: 1.0543x; 1.0048x over previous
//
#include <hip/hip_runtime.h>
#include <math.h>

// ---------------------------------------------------------------------------
// GatedDirGCNConv — r14: r10 structure + (a) K1 2-col register blocking with
// DEFAULT launch bounds (r11's fix minus the VGPR clamp that caused spills),
// (b) K3 4-node gate-MLP batching (r11), (c) pk padding reverted (r13 showed
// zero atomic effect; padding only bloated K3's degree-table footprint).
//   K1 proj_zero : each thread holds TWO weight columns (~145 VGPR, no
//                  spill at default bounds); 4 waves = (side, parity); DS
//                  broadcast b128 count halves (3.2M -> 1.6M chip-wide).
//   K2 edge_w    : unchanged — 1.6M u64-atomic floor (~80 µs).
//   K3 gather_gate: one wave gathers 4 nodes, gate MLP batches 4 nodes per
//                  Wg1q fragment (weight streaming /4); packed pk restores
//                  deg-table L2 residency.
// ---------------------------------------------------------------------------

typedef unsigned long long u64;

#define SLOTS 56   // max row len; P(Poisson(16) >= 56) ~ 5e-15 per side

__device__ __forceinline__ float bflo(unsigned u) { return __uint_as_float(u << 16); }
__device__ __forceinline__ float bfhi(unsigned u) { return __uint_as_float(u & 0xffff0000u); }
__device__ __forceinline__ unsigned rne16(float f) {   // fp32 -> bf16 bits, RNE
    unsigned u = __float_as_uint(f);
    return (u + 0x7fffu + ((u >> 16) & 1u)) >> 16;
}

// K1: fused node projection + zero pk + swizzle Wg1.
// wv = (parity<<1)|side: side picks the weight PAIR {Wl1-half, Ws2d/Wd2s};
// parity picks alternating nodes of the 64-node tile. Each thread owns 2
// weight columns -> per xs float4 broadcast, 2 FMA chains (DS halved).
__global__ __launch_bounds__(256) void proj_zero_kernel(
    const float* __restrict__ x,
    const float* __restrict__ Wl1,  const float* __restrict__ bl1,
    const float* __restrict__ Ws2d, const float* __restrict__ bs2d,
    const float* __restrict__ Wd2s, const float* __restrict__ bd2s,
    const float* __restrict__ Wg1,  float* __restrict__ Wg1q,
    float* __restrict__ A, float* __restrict__ B,
    unsigned* __restrict__ Ah, unsigned* __restrict__ Bh,
    unsigned* __restrict__ HSh, unsigned* __restrict__ HDh,
    int4* __restrict__ zp4, int nz4, int PB, int N)
{
    if (blockIdx.x >= PB) {
        if (blockIdx.x == PB + 64) {               // Wg1 swizzle
            for (int i = threadIdx.x; i < 8192; i += 256) {
                const int k = i >> 6, c = i & 63;
                Wg1q[((k >> 2) * 64 + c) * 4 + (k & 3)] = Wg1[i];
            }
            return;
        }
        const int t0 = (blockIdx.x - PB) * 256 + threadIdx.x;   // zero pk
        const int stride = 64 * 256;
        const int4 z = make_int4(0, 0, 0, 0);
        for (int i = t0; i < nz4; i += stride) zp4[i] = z;
        return;
    }
    __shared__ float xs[64][64];
    const int tid  = threadIdx.x;
    const int n0   = blockIdx.x * 64;
    const int wv   = tid >> 6;
    const int cc   = tid & 63;
    const int side = wv & 1;      // 0: {Wl1a->A/Ah, Ws2d->HSh}; 1: {Wl1b->B/Bh, Wd2s->HDh}
    const int par  = wv >> 1;     // node parity within tile

    const float* W0 = side ? (Wl1 + 64 * 64) : Wl1;
    const float* W1 = side ? Wd2s : Ws2d;
    const float  b0 = side ? 0.f : bl1[cc];
    const float  b1 = side ? bd2s[cc] : bs2d[cc];
    float*    oA  = side ? B  : A;
    unsigned* oAh = side ? Bh : Ah;
    unsigned* oH  = side ? HDh : HSh;

    float w0[64], w1[64];
#pragma unroll
    for (int k = 0; k < 64; ++k) {
        w0[k] = W0[k * 64 + cc];
        w1[k] = W1[k * 64 + cc];
    }

#pragma unroll
    for (int j = 0; j < 4; ++j) {
        int f4  = tid + j * 256;
        int row = f4 >> 4;
        int c4  = f4 & 15;
        int gn  = n0 + row;
        float4 v = (gn < N) ? ((const float4*)x)[(long)gn * 16 + c4]
                            : make_float4(0.f, 0.f, 0.f, 0.f);
        ((float4*)&xs[row][0])[c4] = v;
    }
    __syncthreads();

    const int nmax = (N - n0 < 64) ? (N - n0) : 64;
    for (int n = par; n < nmax; n += 2) {
        float a0 = b0, a1 = b1;
#pragma unroll
        for (int k = 0; k < 64; k += 4) {
            float4 xv = *((const float4*)&xs[n][k]);
            a0 += xv.x * w0[k] + xv.y * w0[k + 1] + xv.z * w0[k + 2] + xv.w * w0[k + 3];
            a1 += xv.x * w1[k] + xv.y * w1[k + 1] + xv.z * w1[k + 2] + xv.w * w1[k + 3];
        }
        const long gn = n0 + n;
        oA[gn * 64 + cc] = a0;
        const float p0 = __shfl_xor(a0, 1);        // partner feature cc^1
        const float p1 = __shfl_xor(a1, 1);
        if ((cc & 1) == 0) {                       // even lane packs (cc, cc+1)
            oAh[gn * 32 + (cc >> 1)] = (rne16(p0) << 16) | rne16(a0);
            oH [gn * 32 + (cc >> 1)] = (rne16(p1) << 16) | rne16(a1);
        }
    }
}

// K2: LCS keep + u64 atomics + direct padded-row record placement.
// pk[0..N) = dst side, pk[N..2N) = src side.  (unchanged — atomic-bound)
#define LCS_MARGIN 0.04f
__global__ __launch_bounds__(256) void edge_w_kernel(
    const int* __restrict__ src, const int* __restrict__ dst,
    const float* __restrict__ counts,
    const float* __restrict__ A, const float* __restrict__ B,
    const unsigned* __restrict__ Ah, const unsigned* __restrict__ Bh,
    const float* __restrict__ Wl2, const float* __restrict__ bl2,
    u64* __restrict__ pk, unsigned* __restrict__ rec, int N, int E)
{
    const int tid = threadIdx.x;
    const int e   = blockIdx.x * 32 + (tid >> 3);
    const int c   = tid & 7;                     // features 8c..8c+7
    if (e >= E) return;

    const int s = src[e];
    const int d = dst[e];
    const uint4  ua  = *((const uint4*)(Ah + (long)s * 32 + c * 4));
    const uint4  ub  = *((const uint4*)(Bh + (long)d * 32 + c * 4));
    const float4 wl0 = *((const float4*)(Wl2 + c * 8));
    const float4 wl1 = *((const float4*)(Wl2 + c * 8 + 4));

    float p = fmaxf(bflo(ua.x) + bflo(ub.x), 0.f) * wl0.x
            + fmaxf(bfhi(ua.x) + bfhi(ub.x), 0.f) * wl0.y
            + fmaxf(bflo(ua.y) + bflo(ub.y), 0.f) * wl0.z
            + fmaxf(bfhi(ua.y) + bfhi(ub.y), 0.f) * wl0.w
            + fmaxf(bflo(ua.z) + bflo(ub.z), 0.f) * wl1.x
            + fmaxf(bfhi(ua.z) + bfhi(ub.z), 0.f) * wl1.y
            + fmaxf(bflo(ua.w) + bflo(ub.w), 0.f) * wl1.z
            + fmaxf(bfhi(ua.w) + bfhi(ub.w), 0.f) * wl1.w;
    p += __shfl_xor(p, 1); p += __shfl_xor(p, 2); p += __shfl_xor(p, 4);

    float z = p + bl2[0];
    if (fabsf(z) < LCS_MARGIN) {        // borderline (~3%): exact fp32 recheck
        const float4 a0 = *((const float4*)(A + (long)s * 64 + c * 8));
        const float4 a1 = *((const float4*)(A + (long)s * 64 + c * 8 + 4));
        const float4 b0 = *((const float4*)(B + (long)d * 64 + c * 8));
        const float4 b1 = *((const float4*)(B + (long)d * 64 + c * 8 + 4));
        float q = fmaxf(a0.x + b0.x, 0.f) * wl0.x + fmaxf(a0.y + b0.y, 0.f) * wl0.y
                + fmaxf(a0.z + b0.z, 0.f) * wl0.z + fmaxf(a0.w + b0.w, 0.f) * wl0.w
                + fmaxf(a1.x + b1.x, 0.f) * wl1.x + fmaxf(a1.y + b1.y, 0.f) * wl1.y
                + fmaxf(a1.z + b1.z, 0.f) * wl1.z + fmaxf(a1.w + b1.w, 0.f) * wl1.w;
        q += __shfl_xor(q, 1); q += __shfl_xor(q, 2); q += __shfl_xor(q, 4);
        z = q + bl2[0];
    }

    if (c == 0) {
        const u64 keep = (z >= 0.f) ? 1ull : 0ull;   // sigmoid(z)>=0.5 <=> z>=0
        const unsigned ic = (unsigned)__float2int_rn(counts[e]);  // {1..4} exact
        const u64 od = atomicAdd(pk + d,     (keep << 32) | (u64)ic);
        const u64 os = atomicAdd(pk + N + s, (keep << 32) | (u64)ic);
        if (keep) {
            rec[(long)d * SLOTS + (int)(od >> 32)]       = ((unsigned)s << 16) | ic;
            rec[(long)(N + s) * SLOTS + (int)(os >> 32)] = ((unsigned)d << 16) | ic;
        }
    }
}

// K3: one wave per 4 nodes; gather each node (8 groups x 8 bf16 feats), then
// the gate MLP batches 4 nodes per Wg1q fragment (weight traffic /4).
__global__ __launch_bounds__(256) void gather_gate_kernel(
    const u64* __restrict__ pk, const unsigned* __restrict__ rec,
    const unsigned* __restrict__ HSh, const unsigned* __restrict__ HDh,
    const float* __restrict__ x,
    const float* __restrict__ Wg1q, const float* __restrict__ bg1,
    const float* __restrict__ Wg2, const float* __restrict__ bg2,
    float* __restrict__ out, int N)
{
    __shared__ float mbuf[16][128];
    const int tid  = threadIdx.x;
    const int wv   = tid >> 6;
    const int lane = tid & 63;
    const int g    = lane >> 3;        // edge group 0..7
    const int c    = lane & 7;         // feature slice: features 8c..8c+7
    const int nb   = blockIdx.x * 16 + wv * 4;     // first node of this wave

    const unsigned* pklo = (const unsigned*)pk;    // lo32 of pk[i] at index 2i

    for (int j = 0; j < 4; ++j) {
        const int n   = nb + j;
        const int row = wv * 4 + j;
        if (n >= N) {
            if (g == 0) {
#pragma unroll
                for (int q = 0; q < 8; ++q) {
                    mbuf[row][c * 8 + q]      = 0.f;
                    mbuf[row][64 + c * 8 + q] = 0.f;
                }
            }
            continue;
        }

        const u64 pin  = pk[n];
        const u64 pout = pk[N + n];
        const int ei = (int)(pin >> 32);
        const int eo = (int)(pout >> 32);
        const float qin  = 1.f / sqrtf(fmaxf((float)(unsigned)pin,  1.f)); // isq_in[n]
        const float qout = 1.f / sqrtf(fmaxf((float)(unsigned)pout, 1.f)); // isq_out[n]
        const unsigned* rin  = rec + (long)n * SLOTS;
        const unsigned* rout = rec + (long)(N + n) * SLOTS;

        float mi[8], mo[8];
#pragma unroll
        for (int q = 0; q < 8; ++q) { mi[q] = 0.f; mo[q] = 0.f; }

        int ii = g, jo = g;
        while ((ii < ei) || (jo < eo)) {
            const bool pa = ii < ei;
            const bool pb = jo < eo;
            const unsigned ra = rin[pa ? ii : 0];      // clamped: slot0 junk*0 safe
            const unsigned rb = rout[pb ? jo : 0];
            const unsigned sa = ra >> 16;              // src node (m_in side)
            const unsigned sb = rb >> 16;              // dst node (m_out side)
            // w/row-factor: cnt * rsqrt(deg of the other endpoint)
            const float dga = (float)pklo[2 * (N + (int)sa)];   // deg_out[sa]
            const float dgb = (float)pklo[2 * (int)sb];         // deg_in[sb]
            const float wa = pa ? (float)(ra & 0xFFu) * (1.f / sqrtf(fmaxf(dga, 1.f))) : 0.f;
            const float wb = pb ? (float)(rb & 0xFFu) * (1.f / sqrtf(fmaxf(dgb, 1.f))) : 0.f;
            const uint4 ua = *((const uint4*)(HSh + (long)sa * 32 + c * 4));
            const uint4 ub = *((const uint4*)(HDh + (long)sb * 32 + c * 4));
            mi[0] += wa * bflo(ua.x);  mo[0] += wb * bflo(ub.x);
            mi[1] += wa * bfhi(ua.x);  mo[1] += wb * bfhi(ub.x);
            mi[2] += wa * bflo(ua.y);  mo[2] += wb * bflo(ub.y);
            mi[3] += wa * bfhi(ua.y);  mo[3] += wb * bfhi(ub.y);
            mi[4] += wa * bflo(ua.z);  mo[4] += wb * bflo(ub.z);
            mi[5] += wa * bfhi(ua.z);  mo[5] += wb * bfhi(ub.z);
            mi[6] += wa * bflo(ua.w);  mo[6] += wb * bflo(ub.w);
            mi[7] += wa * bfhi(ua.w);  mo[7] += wb * bfhi(ub.w);
            ii += 8; jo += 8;
        }

        // reduce the 8 edge groups (lane bits 3,4,5)
#pragma unroll
        for (int q = 0; q < 8; ++q) {
            mi[q] += __shfl_xor(mi[q], 8);
            mi[q] += __shfl_xor(mi[q], 16);
            mi[q] += __shfl_xor(mi[q], 32);
            mo[q] += __shfl_xor(mo[q], 8);
            mo[q] += __shfl_xor(mo[q], 16);
            mo[q] += __shfl_xor(mo[q], 32);
        }
        if (g == 0) {
#pragma unroll
            for (int q = 0; q < 8; ++q) {
                mbuf[row][c * 8 + q]      = mi[q] * qin;    // apply row norm factor
                mbuf[row][64 + c * 8 + q] = mo[q] * qout;
            }
        }
    }
    // wave-local LDS RAW; compiler inserts lgkmcnt wait (no barrier needed)

    const float bgv = bg1[lane];
    float ac0 = bgv, ac1 = bgv, ac2 = bgv, ac3 = bgv;
    const float* m0 = &mbuf[wv * 4 + 0][0];
    const float* m1 = &mbuf[wv * 4 + 1][0];
    const float* m2 = &mbuf[wv * 4 + 2][0];
    const float* m3 = &mbuf[wv * 4 + 3][0];
#pragma unroll 4
    for (int k4 = 0; k4 < 32; ++k4) {
        const float4 w4 = ((const float4*)Wg1q)[k4 * 64 + lane];   // coalesced, L1
        const float4 q0 = ((const float4*)m0)[k4];                 // LDS broadcast
        const float4 q1 = ((const float4*)m1)[k4];
        const float4 q2 = ((const float4*)m2)[k4];
        const float4 q3 = ((const float4*)m3)[k4];
        ac0 += q0.x * w4.x + q0.y * w4.y + q0.z * w4.z + q0.w * w4.w;
        ac1 += q1.x * w4.x + q1.y * w4.y + q1.z * w4.z + q1.w * w4.w;
        ac2 += q2.x * w4.x + q2.y * w4.y + q2.z * w4.z + q2.w * w4.w;
        ac3 += q3.x * w4.x + q3.y * w4.y + q3.z * w4.z + q3.w * w4.w;
    }
    const float wg2 = Wg2[lane];
    float v0 = fmaxf(ac0, 0.f) * wg2;
    float v1 = fmaxf(ac1, 0.f) * wg2;
    float v2 = fmaxf(ac2, 0.f) * wg2;
    float v3 = fmaxf(ac3, 0.f) * wg2;
#pragma unroll
    for (int m = 1; m <= 32; m <<= 1) {
        v0 += __shfl_xor(v0, m);
        v1 += __shfl_xor(v1, m);
        v2 += __shfl_xor(v2, m);
        v3 += __shfl_xor(v3, m);
    }
    const float bb = bg2[0];
    float gt[4];
    gt[0] = 1.f / (1.f + expf(-(v0 + bb)));
    gt[1] = 1.f / (1.f + expf(-(v1 + bb)));
    gt[2] = 1.f / (1.f + expf(-(v2 + bb)));
    gt[3] = 1.f / (1.f + expf(-(v3 + bb)));

#pragma unroll
    for (int j = 0; j < 4; ++j) {
        const int n = nb + j;
        if (n >= N) continue;
        const float miv = mbuf[wv * 4 + j][lane];
        const float mov = mbuf[wv * 4 + j][64 + lane];
        out[(long)n * 64 + lane] = 0.5f * gt[j] * miv + 0.5f * (1.f - gt[j]) * mov
                                 + x[(long)n * 64 + lane];
    }
}

extern "C" void kernel_launch(void* const* d_in, const int* in_sizes, int n_in,
                              void* d_out, int out_size, void* d_ws, size_t ws_size,
                              hipStream_t stream) {
    const float* x      = (const float*)d_in[0];
    const float* counts = (const float*)d_in[1];
    const float* Ws2d   = (const float*)d_in[2];
    const float* bs2d   = (const float*)d_in[3];
    const float* Wd2s   = (const float*)d_in[4];
    const float* bd2s   = (const float*)d_in[5];
    const float* Wl1    = (const float*)d_in[6];
    const float* bl1    = (const float*)d_in[7];
    const float* Wl2    = (const float*)d_in[8];
    const float* bl2    = (const float*)d_in[9];
    const float* Wg1    = (const float*)d_in[10];
    const float* bg1    = (const float*)d_in[11];
    const float* Wg2    = (const float*)d_in[12];
    const float* bg2    = (const float*)d_in[13];
    const int*   src    = (const int*)d_in[14];
    const int*   dst    = (const int*)d_in[15];

    const int N  = in_sizes[0] / 64;
    const int E  = in_sizes[14];
    const int PB = (N + 63) / 64;              // proj blocks

    float* ws      = (float*)d_ws;
    float* Wg1q    = ws;                       // 8192 floats
    float* A       = ws + 8192;                // 64N fp32
    float* B       = A + 64L * N;              // 64N fp32
    unsigned* Ah   = (unsigned*)(B + 64L * N); // 32N packed bf16
    unsigned* Bh   = Ah + 32L * N;
    unsigned* HSh  = Bh + 32L * N;
    unsigned* HDh  = HSh + 32L * N;
    u64* pk        = (u64*)(HDh + 32L * N);    // 2N u64 (even offset -> 8B ok)
    unsigned* rec  = (unsigned*)(pk + 2L * N); // 2N * SLOTS u32 (padded rows)

    proj_zero_kernel<<<PB + 65, 256, 0, stream>>>(
        x, Wl1, bl1, Ws2d, bs2d, Wd2s, bd2s, Wg1, Wg1q,
        A, B, Ah, Bh, HSh, HDh, (int4*)pk, N, PB, N);   // 2N u64 = N int4

    edge_w_kernel<<<(E + 31) / 32, 256, 0, stream>>>(
        src, dst, counts, A, B, Ah, Bh, Wl2, bl2, pk, rec, N, E);

    gather_gate_kernel<<<(N + 15) / 16, 256, 0, stream>>>(
        pk, rec, HSh, HDh, x, Wg1q, bg1, Wg2, bg2, (float*)d_out, N);
}